// Round 7
// baseline (398.686 us; speedup 1.0000x reference)
//
#include <hip/hip_runtime.h>
#include <hip/hip_fp16.h>

#define HID 64
#define BN_EPS 1e-5f
#define WINSH 8          // 256 nodes per dst-window
#define WINSZ 256
#define B1 256           // bucketing blocks
#define PIT 72           // LDS pitch in shorts (16B-aligned fragment reads)

typedef short bf16x8 __attribute__((ext_vector_type(8)));
typedef float f32x4 __attribute__((ext_vector_type(4)));

__device__ __forceinline__ unsigned short f2b(float f) {
    unsigned int u = __float_as_uint(f);
    u = (u + 0x7FFF + ((u >> 16) & 1)) >> 16;   // RNE
    return (unsigned short)u;
}
__device__ __forceinline__ float b2f(unsigned short h) {
    return __uint_as_float(((unsigned int)h) << 16);
}
__device__ __forceinline__ f32x4 mfma_bf16(bf16x8 a, bf16x8 b, f32x4 c) {
    return __builtin_amdgcn_mfma_f32_16x16x32_bf16(a, b, c, 0, 0, 0);
}

// ---------------------------------------------------------------------------
// prep: blocks 0-6 = weight split; block 7 = zero stats; blocks 8+ = histogram
// ---------------------------------------------------------------------------
__global__ __launch_bounds__(256) void prep_kernel(const float* __restrict__ w2a,
                                                   const float* __restrict__ w1s,
                                                   const float* __restrict__ w2s,
                                                   unsigned short* __restrict__ whi,
                                                   unsigned short* __restrict__ wlo,
                                                   float* __restrict__ stats,
                                                   const int* __restrict__ dst,
                                                   int* __restrict__ cnt,
                                                   int E, int nw, int chunk) {
    int blk = blockIdx.x, tid = threadIdx.x;
    if (blk < 7) {
        const float* srcm = (blk == 0) ? w2a : (blk <= 3 ? w1s + (size_t)(blk - 1) * 4096
                                                         : w2s + (size_t)(blk - 4) * 4096);
        unsigned short* dh = whi + (size_t)blk * 4096;
        unsigned short* dl = wlo + (size_t)blk * 4096;
        for (int idx = tid; idx < 4096; idx += 256) {
            int j = idx & 7;
            int lane = (idx >> 3) & 63;
            int ntkh = idx >> 9;
            int nt = ntkh >> 1, kh = ntkh & 1;
            int nc = nt * 16 + (lane & 15);
            int k = kh * 32 + (lane >> 4) * 8 + j;
            float v = srcm[k * 64 + nc];
            unsigned short h = f2b(v);
            dh[idx] = h;
            dl[idx] = f2b(v - b2f(h));
        }
    } else if (blk == 7) {
        stats[tid] = 0.f;
        stats[tid + 256] = 0.f;
    } else {
        __shared__ int c[256];
        int b = blk - 8;
        c[tid] = 0;
        __syncthreads();
        int lo = b * chunk;
        int hi = lo + chunk; if (hi > E) hi = E;
        if ((((size_t)(dst + lo)) & 15) == 0) {
            int n4 = (hi - lo) >> 2;
            const int4* d4p = (const int4*)(dst + lo);
            for (int g = tid; g < n4; g += 256) {
                int4 d4 = d4p[g];
                atomicAdd(&c[d4.x >> WINSH], 1);
                atomicAdd(&c[d4.y >> WINSH], 1);
                atomicAdd(&c[d4.z >> WINSH], 1);
                atomicAdd(&c[d4.w >> WINSH], 1);
            }
            for (int e = lo + (n4 << 2) + tid; e < hi; e += 256)
                atomicAdd(&c[dst[e] >> WINSH], 1);
        } else {
            for (int e = lo + tid; e < hi; e += 256) atomicAdd(&c[dst[e] >> WINSH], 1);
        }
        __syncthreads();
        if (tid < nw) cnt[tid * B1 + b] = c[tid];
    }
}

// ---------------------------------------------------------------------------
// scan_a: per-256-cell block scan; emits partial prefixes + per-block sums.
// The tiny 196-wide scan of blocksums is recomputed locally inside p3/p4.
// ---------------------------------------------------------------------------
__global__ __launch_bounds__(256) void scan_a_kernel(const int* __restrict__ in,
                                                     int* __restrict__ partial,
                                                     int* __restrict__ blocksum, int n) {
    __shared__ int sums[256];
    int tid = threadIdx.x;
    int i = blockIdx.x * 256 + tid;
    int v = (i < n) ? in[i] : 0;
    sums[tid] = v;
    __syncthreads();
    for (int off = 1; off < 256; off <<= 1) {
        int t = (tid >= off) ? sums[tid - off] : 0;
        __syncthreads();
        sums[tid] += t;
        __syncthreads();
    }
    if (i < n) partial[i] = sums[tid] - v;
    if (tid == 255) blocksum[blockIdx.x] = sums[255];
}

__global__ __launch_bounds__(256) void p3_bucket_kernel(const int* __restrict__ src,
                                                        const int* __restrict__ dst,
                                                        const int* __restrict__ cpart,
                                                        const int* __restrict__ bsum,
                                                        int* __restrict__ ebuf,
                                                        int E, int nw, int chunk, int nbs2) {
    __shared__ int cur[256];
    __shared__ int sc[256];
    int tid = threadIdx.x, b = blockIdx.x;
    // local exclusive scan of bsum (nbs2 <= 256)
    int v = (tid < nbs2) ? bsum[tid] : 0;
    sc[tid] = v;
    __syncthreads();
    for (int off = 1; off < 256; off <<= 1) {
        int t = (tid >= off) ? sc[tid - off] : 0;
        __syncthreads();
        sc[tid] += t;
        __syncthreads();
    }
    int excl = sc[tid] - v;
    if (tid < nw) cur[tid] = cpart[tid * B1 + b] + excl;
    __syncthreads();
    int lo = b * chunk;
    int hi = lo + chunk; if (hi > E) hi = E;
    if (((((size_t)(dst + lo)) | ((size_t)(src + lo))) & 15) == 0) {
        int n4 = (hi - lo) >> 2;
        const int4* d4p = (const int4*)(dst + lo);
        const int4* s4p = (const int4*)(src + lo);
        for (int g = tid; g < n4; g += 256) {
            int4 d4 = d4p[g];
            int4 s4 = s4p[g];
            int p0 = atomicAdd(&cur[d4.x >> WINSH], 1);
            ebuf[p0] = s4.x | ((d4.x & (WINSZ - 1)) << 24);
            int p1 = atomicAdd(&cur[d4.y >> WINSH], 1);
            ebuf[p1] = s4.y | ((d4.y & (WINSZ - 1)) << 24);
            int p2 = atomicAdd(&cur[d4.z >> WINSH], 1);
            ebuf[p2] = s4.z | ((d4.z & (WINSZ - 1)) << 24);
            int p3 = atomicAdd(&cur[d4.w >> WINSH], 1);
            ebuf[p3] = s4.w | ((d4.w & (WINSZ - 1)) << 24);
        }
        for (int e = lo + (n4 << 2) + tid; e < hi; e += 256) {
            int d = dst[e];
            int pos = atomicAdd(&cur[d >> WINSH], 1);
            ebuf[pos] = src[e] | ((d & (WINSZ - 1)) << 24);
        }
    } else {
        for (int e = lo + tid; e < hi; e += 256) {
            int d = dst[e];
            int pos = atomicAdd(&cur[d >> WINSH], 1);
            ebuf[pos] = src[e] | ((d & (WINSZ - 1)) << 24);
        }
    }
}

// ---------------------------------------------------------------------------
// p4_fine: window-local counting sort into csr_src + layer-1 aggregation
// (xacc[dstlocal] += x[src], LDS float atomics) folded into the scatter.
// Emits rowptr/deg and zscalar = (1+eps0)*x + sum.
// ---------------------------------------------------------------------------
__global__ __launch_bounds__(256) void p4_fine_kernel(const int* __restrict__ ebuf,
                                                      const int* __restrict__ cpart,
                                                      const int* __restrict__ bsum,
                                                      const float* __restrict__ x,
                                                      const float* __restrict__ eps,
                                                      int* __restrict__ csr_src,
                                                      int* __restrict__ rowptr,
                                                      int* __restrict__ deg,
                                                      float* __restrict__ zscalar,
                                                      int E, int n, int nw, int nbs2) {
    __shared__ int fcnt[256];
    __shared__ int foff[256];
    __shared__ float xacc[256];
    int tid = threadIdx.x, w = blockIdx.x;
    // local exclusive scan of bsum -> blockoff values for w and w+1
    int bv = (tid < nbs2) ? bsum[tid] : 0;
    foff[tid] = bv;
    __syncthreads();
    for (int off = 1; off < 256; off <<= 1) {
        int t = (tid >= off) ? foff[tid - off] : 0;
        __syncthreads();
        foff[tid] += t;
        __syncthreads();
    }
    int excl = foff[tid] - bv;
    __syncthreads();
    foff[tid] = excl;
    __syncthreads();
    int lo = cpart[w * B1] + foff[w];
    int hi = (w + 1 < nw) ? cpart[(w + 1) * B1] + foff[w + 1] : E;
    __syncthreads();
    fcnt[tid] = 0;
    xacc[tid] = 0.f;
    __syncthreads();
    for (int e = lo + tid; e < hi; e += 256) atomicAdd(&fcnt[(unsigned)ebuf[e] >> 24], 1);
    __syncthreads();
    int v = fcnt[tid];
    foff[tid] = v;
    __syncthreads();
    for (int off = 1; off < 256; off <<= 1) {
        int t = (tid >= off) ? foff[tid - off] : 0;
        __syncthreads();
        foff[tid] += t;
        __syncthreads();
    }
    int myoff = lo + foff[tid] - v;
    int node = w * WINSZ + tid;
    if (node < n) { rowptr[node] = myoff; deg[node] = v; }
    __syncthreads();
    fcnt[tid] = myoff;
    __syncthreads();
    for (int e = lo + tid; e < hi; e += 256) {
        int p = ebuf[e];
        int s = p & 0xFFFFFF;
        int dl = (unsigned)p >> 24;
        int pos = atomicAdd(&fcnt[dl], 1);   // LDS atomic
        csr_src[pos] = s;
        atomicAdd(&xacc[dl], x[s]);          // LDS float atomic (layer-1 agg)
    }
    __syncthreads();
    if (node < n) zscalar[node] = fmaf(1.0f + eps[0], x[node], xacc[tid]);
}

// ---------------------------------------------------------------------------
// gatherz (wide datapath): lane = 4 edge-slots x 16 feature-quads; each lane
// loads 8B (4 features) per edge -> half the VMEM instructions of the half2
// version, same bytes, 2x lines in flight per instruction. 32-edge main loop
// keeps 8 loads outstanding. BN of prev layer inline; fp16 z output.
// ---------------------------------------------------------------------------
__global__ __launch_bounds__(256) void gatherz_kernel(const __half* __restrict__ hh16,
                                                      const float* __restrict__ stats_prev,
                                                      const float* __restrict__ gamma_prev,
                                                      const float* __restrict__ beta_prev,
                                                      const int* __restrict__ rowptr,
                                                      const int* __restrict__ deg,
                                                      const int* __restrict__ csr_src,
                                                      const float* __restrict__ eps,
                                                      int layer,
                                                      __half* __restrict__ zh16, int n) {
    int lane = threadIdx.x & 63;
    int es = lane >> 4;            // edge slot 0..3
    int fq = lane & 15;            // feature quad (features 4fq .. 4fq+3)
    int node = blockIdx.x * 4 + (threadIdx.x >> 6);

    // BN params of previous layer for this feature quad
    float inv_n = 1.0f / (float)n;
    float4 smv = ((const float4*)stats_prev)[fq];
    float4 sqv = ((const float4*)(stats_prev + 64))[fq];
    float4 gmv = ((const float4*)gamma_prev)[fq];
    float4 btv = ((const float4*)beta_prev)[fq];
    float mu0 = smv.x * inv_n, mu1 = smv.y * inv_n;
    float mu2 = smv.z * inv_n, mu3 = smv.w * inv_n;
    float sc0 = gmv.x * rsqrtf(sqv.x * inv_n - mu0 * mu0 + BN_EPS);
    float sc1 = gmv.y * rsqrtf(sqv.y * inv_n - mu1 * mu1 + BN_EPS);
    float sc2 = gmv.z * rsqrtf(sqv.z * inv_n - mu2 * mu2 + BN_EPS);
    float sc3 = gmv.w * rsqrtf(sqv.w * inv_n - mu3 * mu3 + BN_EPS);
    float sh0 = btv.x - mu0 * sc0;
    float sh1 = btv.y - mu1 * sc1;
    float sh2 = btv.z - mu2 * sc2;
    float sh3 = btv.w - mu3 * sc3;

    if (node >= n) return;
    int start = __builtin_amdgcn_readfirstlane(rowptr[node]);
    int cnt   = __builtin_amdgcn_readfirstlane(deg[node]);

    const float2* T2 = (const float2*)hh16;   // row = 16 float2 (128 B)
    float a00=0.f,a01=0.f,a02=0.f,a03=0.f, a10=0.f,a11=0.f,a12=0.f,a13=0.f;
    float a20=0.f,a21=0.f,a22=0.f,a23=0.f, a30=0.f,a31=0.f,a32=0.f,a33=0.f;
    float a40=0.f,a41=0.f,a42=0.f,a43=0.f, a50=0.f,a51=0.f,a52=0.f,a53=0.f;
    float a60=0.f,a61=0.f,a62=0.f,a63=0.f, a70=0.f,a71=0.f,a72=0.f,a73=0.f;

#define GACC(r, A0, A1, A2, A3)                                        \
    {                                                                  \
        float2 u = T2[(size_t)(r) * 16 + fq];                          \
        float2 f0 = __half22float2(((const __half2*)&u)[0]);           \
        float2 f1 = __half22float2(((const __half2*)&u)[1]);           \
        A0 += f0.x; A1 += f0.y; A2 += f1.x; A3 += f1.y;                \
    }

    int e = 0;
    for (; e + 32 <= cnt; e += 32) {
        int i0 = start + e + es;
        int r0 = csr_src[i0];
        int r1 = csr_src[i0 + 4];
        int r2 = csr_src[i0 + 8];
        int r3 = csr_src[i0 + 12];
        int r4 = csr_src[i0 + 16];
        int r5 = csr_src[i0 + 20];
        int r6 = csr_src[i0 + 24];
        int r7 = csr_src[i0 + 28];
        GACC(r0, a00, a01, a02, a03);
        GACC(r1, a10, a11, a12, a13);
        GACC(r2, a20, a21, a22, a23);
        GACC(r3, a30, a31, a32, a33);
        GACC(r4, a40, a41, a42, a43);
        GACC(r5, a50, a51, a52, a53);
        GACC(r6, a60, a61, a62, a63);
        GACC(r7, a70, a71, a72, a73);
    }
    for (; e + 16 <= cnt; e += 16) {
        int i0 = start + e + es;
        int r0 = csr_src[i0];
        int r1 = csr_src[i0 + 4];
        int r2 = csr_src[i0 + 8];
        int r3 = csr_src[i0 + 12];
        GACC(r0, a00, a01, a02, a03);
        GACC(r1, a10, a11, a12, a13);
        GACC(r2, a20, a21, a22, a23);
        GACC(r3, a30, a31, a32, a33);
    }
    for (int i = e + es; i < cnt; i += 4) {
        int r = csr_src[start + i];
        GACC(r, a00, a01, a02, a03);
    }
#undef GACC

    float s0 = ((a00 + a10) + (a20 + a30)) + ((a40 + a50) + (a60 + a70));
    float s1 = ((a01 + a11) + (a21 + a31)) + ((a41 + a51) + (a61 + a71));
    float s2 = ((a02 + a12) + (a22 + a32)) + ((a42 + a52) + (a62 + a72));
    float s3 = ((a03 + a13) + (a23 + a33)) + ((a43 + a53) + (a63 + a73));
    s0 += __shfl_xor(s0, 16); s0 += __shfl_xor(s0, 32);
    s1 += __shfl_xor(s1, 16); s1 += __shfl_xor(s1, 32);
    s2 += __shfl_xor(s2, 16); s2 += __shfl_xor(s2, 32);
    s3 += __shfl_xor(s3, 16); s3 += __shfl_xor(s3, 32);

    float ep = 1.0f + eps[layer];
    float cf = (float)cnt;
    float2 su = T2[(size_t)node * 16 + fq];
    float2 sf0 = __half22float2(((const __half2*)&su)[0]);
    float2 sf1 = __half22float2(((const __half2*)&su)[1]);
    float z0 = fmaf(sc0, fmaf(ep, sf0.x, s0), sh0 * (ep + cf));
    float z1 = fmaf(sc1, fmaf(ep, sf0.y, s1), sh1 * (ep + cf));
    float z2 = fmaf(sc2, fmaf(ep, sf1.x, s2), sh2 * (ep + cf));
    float z3 = fmaf(sc3, fmaf(ep, sf1.y, s3), sh3 * (ep + cf));
    if (es == 0) {
        float2 o;
        ((__half2*)&o)[0] = __floats2half2_rn(z0, z1);
        ((__half2*)&o)[1] = __floats2half2_rn(z2, z3);
        ((float2*)zh16)[(size_t)node * 16 + fq] = o;
    }
}

// ---------------------------------------------------------------------------
// MFMA MLP, split-bf16 precision. mode 1 stages from fp16 z (exact split of
// the fp16 value). Epilogue writes hh16 (layers 1-3) and/or hpre (layer 4).
// ---------------------------------------------------------------------------
__global__ __launch_bounds__(256) void mlp_kernel(const __half* __restrict__ zh16,
                                                  const float* __restrict__ zscalar,
                                                  const float* __restrict__ w1a,
                                                  const float* __restrict__ b1a,
                                                  const unsigned short* __restrict__ w1h,
                                                  const unsigned short* __restrict__ w1l,
                                                  const float* __restrict__ b1v,
                                                  const unsigned short* __restrict__ w2h,
                                                  const unsigned short* __restrict__ w2l,
                                                  const float* __restrict__ b2v,
                                                  float* __restrict__ hpre,
                                                  __half* __restrict__ hh16,
                                                  float* __restrict__ stats,
                                                  int n, int mode,
                                                  int write_hpre, int write_hh) {
    __shared__ __align__(16) unsigned short Ah[64 * PIT];
    __shared__ __align__(16) unsigned short Al[64 * PIT];
    __shared__ float ssum[64], ssq[64];

    int tid = threadIdx.x;
    int base = blockIdx.x * 64;

    if (mode) {
        const unsigned int* z32 = (const unsigned int*)zh16;
        for (int i = tid; i < 2048; i += 256) {
            int nn = i >> 5, c = i & 31;
            unsigned int u = z32[(size_t)(base + nn) * 32 + c];
            __half2 hv = *(__half2*)&u;
            float vx = __half2float(hv.x);
            float vy = __half2float(hv.y);
            unsigned short hx = f2b(vx);
            unsigned short hy = f2b(vy);
            Ah[nn * PIT + 2 * c]     = hx;
            Ah[nn * PIT + 2 * c + 1] = hy;
            Al[nn * PIT + 2 * c]     = f2b(vx - b2f(hx));
            Al[nn * PIT + 2 * c + 1] = f2b(vy - b2f(hy));
        }
    } else {
        for (int i = tid; i < 4096; i += 256) {
            int nn = i >> 6, k = i & 63;
            float zv = zscalar[base + nn];
            float v = fmaxf(fmaf(zv, w1a[k], b1a[k]), 0.f);
            unsigned short h = f2b(v);
            Ah[nn * PIT + k] = h;
            Al[nn * PIT + k] = f2b(v - b2f(h));
        }
    }
    if (tid < 64) { ssum[tid] = 0.f; ssq[tid] = 0.f; }
    __syncthreads();

    int l = tid & 63;
    int m = l & 15;            // A/B free index; D col
    int q = l >> 4;            // quad; D row block
    int m0 = (tid >> 6) * 16;  // wave's node-row block

    const bf16x8* a0h = (const bf16x8*)&Ah[(m0 + m) * PIT + q * 8];
    const bf16x8* a1h = (const bf16x8*)&Ah[(m0 + m) * PIT + 32 + q * 8];
    const bf16x8* a0l = (const bf16x8*)&Al[(m0 + m) * PIT + q * 8];
    const bf16x8* a1l = (const bf16x8*)&Al[(m0 + m) * PIT + 32 + q * 8];

    if (mode) {
        // GEMM1: T = relu(Z @ W1 + b1), split arithmetic
        bf16x8 xa0h = *a0h, xa1h = *a1h, xa0l = *a0l, xa1l = *a1l;
        f32x4 acc[4];
#pragma unroll
        for (int nt = 0; nt < 4; ++nt) {
            size_t fo0 = ((size_t)(nt * 2 + 0) * 64 + l) * 8;
            size_t fo1 = ((size_t)(nt * 2 + 1) * 64 + l) * 8;
            bf16x8 b0h = *(const bf16x8*)(w1h + fo0);
            bf16x8 b1h_ = *(const bf16x8*)(w1h + fo1);
            bf16x8 b0l = *(const bf16x8*)(w1l + fo0);
            bf16x8 b1l_ = *(const bf16x8*)(w1l + fo1);
            f32x4 c = {0.f, 0.f, 0.f, 0.f};
            c = mfma_bf16(xa0h, b0h, c);
            c = mfma_bf16(xa0h, b0l, c);
            c = mfma_bf16(xa0l, b0h, c);
            c = mfma_bf16(xa1h, b1h_, c);
            c = mfma_bf16(xa1h, b1l_, c);
            c = mfma_bf16(xa1l, b1h_, c);
            acc[nt] = c;
        }
#pragma unroll
        for (int nt = 0; nt < 4; ++nt) {
            int col = nt * 16 + m;
            float bv = b1v[col];
#pragma unroll
            for (int r = 0; r < 4; ++r) {
                int row = m0 + q * 4 + r;
                float T = fmaxf(acc[nt][r] + bv, 0.f);
                unsigned short h = f2b(T);
                Ah[row * PIT + col] = h;
                Al[row * PIT + col] = f2b(T - b2f(h));
            }
        }
    }
    __syncthreads();

    // GEMM2: H = relu(T @ W2 + b2), split arithmetic
    {
        bf16x8 xa0h = *a0h, xa1h = *a1h, xa0l = *a0l, xa1l = *a1l;
        f32x4 acc[4];
#pragma unroll
        for (int nt = 0; nt < 4; ++nt) {
            size_t fo0 = ((size_t)(nt * 2 + 0) * 64 + l) * 8;
            size_t fo1 = ((size_t)(nt * 2 + 1) * 64 + l) * 8;
            bf16x8 b0h = *(const bf16x8*)(w2h + fo0);
            bf16x8 b1h_ = *(const bf16x8*)(w2h + fo1);
            bf16x8 b0l = *(const bf16x8*)(w2l + fo0);
            bf16x8 b1l_ = *(const bf16x8*)(w2l + fo1);
            f32x4 c = {0.f, 0.f, 0.f, 0.f};
            c = mfma_bf16(xa0h, b0h, c);
            c = mfma_bf16(xa0h, b0l, c);
            c = mfma_bf16(xa0l, b0h, c);
            c = mfma_bf16(xa1h, b1h_, c);
            c = mfma_bf16(xa1h, b1l_, c);
            c = mfma_bf16(xa1l, b1h_, c);
            acc[nt] = c;
        }
#pragma unroll
        for (int nt = 0; nt < 4; ++nt) {
            int col = nt * 16 + m;
            float bv = b2v[col];
            float cs = 0.f, cq = 0.f;
#pragma unroll
            for (int r = 0; r < 4; ++r) {
                int node = base + m0 + q * 4 + r;
                float h = fmaxf(acc[nt][r] + bv, 0.f);
                if (node < n) {
                    if (write_hpre) hpre[(size_t)node * HID + col] = h;
                    if (write_hh) hh16[(size_t)node * HID + col] = __float2half(h);
                    cs += h;
                    cq = fmaf(h, h, cq);
                }
            }
            cs += __shfl_xor(cs, 16); cs += __shfl_xor(cs, 32);
            cq += __shfl_xor(cq, 16); cq += __shfl_xor(cq, 32);
            if (q == 0) {
                atomicAdd(&ssum[col], cs);
                atomicAdd(&ssq[col], cq);
            }
        }
    }
    __syncthreads();
    if (tid < 64) {
        atomicAdd(&stats[tid], ssum[tid]);
        atomicAdd(&stats[64 + tid], ssq[tid]);
    }
}

// ---------------------------------------------------------------------------
// Final: BN of layer 4 from stats + fc dot.
// ---------------------------------------------------------------------------
__global__ __launch_bounds__(256) void final_kernel(const float* __restrict__ hpre,
                                                    const float* __restrict__ stats,
                                                    const float* __restrict__ gamma,
                                                    const float* __restrict__ beta,
                                                    const float* __restrict__ fcw,
                                                    const float* __restrict__ fcb,
                                                    float* __restrict__ out, int n) {
    int wave = threadIdx.x >> 6;
    int lane = threadIdx.x & 63;
    int node = blockIdx.x * 4 + wave;
    if (node < n) {
        float inv_n = 1.0f / (float)n;
        float mu = stats[lane] * inv_n;
        float var = stats[64 + lane] * inv_n - mu * mu;
        float inv = rsqrtf(var + BN_EPS);
        float sc = gamma[lane] * inv;
        float sh = beta[lane] - mu * sc;
        float v = hpre[(size_t)node * HID + lane];
        float t = fmaf(v, sc, sh) * fcw[lane];
        for (int off = 32; off > 0; off >>= 1) t += __shfl_xor(t, off);
        if (lane == 0) out[node] = t + fcb[0];
    }
}

// ---------------------------------------------------------------------------
extern "C" void kernel_launch(void* const* d_in, const int* in_sizes, int n_in,
                              void* d_out, int out_size, void* d_ws, size_t ws_size,
                              hipStream_t stream) {
    const float* x      = (const float*)d_in[0];
    const int*   ei     = (const int*)d_in[1];
    const float* w1a    = (const float*)d_in[2];
    const float* b1a    = (const float*)d_in[3];
    const float* w2a    = (const float*)d_in[4];
    const float* b2a    = (const float*)d_in[5];
    const float* w1s    = (const float*)d_in[6];
    const float* b1s    = (const float*)d_in[7];
    const float* w2s    = (const float*)d_in[8];
    const float* b2s    = (const float*)d_in[9];
    const float* eps    = (const float*)d_in[10];
    const float* gammas = (const float*)d_in[11];
    const float* betas  = (const float*)d_in[12];
    const float* fcw    = (const float*)d_in[13];
    const float* fcb    = (const float*)d_in[14];
    float* out = (float*)d_out;

    int n = in_sizes[0];          // 50000
    int E = in_sizes[1] / 2;      // 1600000
    int npad = ((n + 63) / 64) * 64;
    int nblk = npad / 64;

    int nw = (n + WINSZ - 1) >> WINSH;      // 196 windows
    int NWB = nw * B1;
    int chunk = (((E + B1 - 1) / B1) + 3) & ~3;   // 4-aligned for int4 path
    int nbs2 = (NWB + 255) / 256;

    const int* src = ei;
    const int* dst = ei + E;

    char* p = (char*)d_ws;
    float* csrtmp  = (float*)p; p += (size_t)npad * HID * 4;   // CSR temps region
    float* hpre    = (float*)p; p += (size_t)npad * HID * 4;
    __half* hh16   = (__half*)p; p += (size_t)npad * HID * 2;
    __half* zh16   = (__half*)p; p += (size_t)npad * HID * 2;
    float* zscalar = (float*)p; p += (size_t)npad * 4;
    float* stats   = (float*)p; p += 4 * 128 * 4;
    unsigned short* whi = (unsigned short*)p; p += 7 * 4096 * 2;
    unsigned short* wlo = (unsigned short*)p; p += 7 * 4096 * 2;
    int* deg     = (int*)p; p += (size_t)n * 4;
    int* rowptr  = (int*)p; p += (size_t)n * 4;
    int* csr_src = (int*)p; p += (size_t)E * 4;

    // CSR-build temporaries live in csrtmp (dead after p4)
    int* ebuf     = (int*)csrtmp;
    int* cnt      = ebuf + E;
    int* cpart    = cnt + NWB;
    int* bsum     = cpart + NWB;

    // ---- prep (weights + stats zero + histogram) + CSR build ----
    prep_kernel<<<8 + B1, 256, 0, stream>>>(w2a, w1s, w2s, whi, wlo, stats,
                                            dst, cnt, E, nw, chunk);
    scan_a_kernel<<<nbs2, 256, 0, stream>>>(cnt, cpart, bsum, NWB);
    p3_bucket_kernel<<<B1, 256, 0, stream>>>(src, dst, cpart, bsum, ebuf, E, nw, chunk, nbs2);
    p4_fine_kernel<<<nw, 256, 0, stream>>>(ebuf, cpart, bsum, x, eps, csr_src, rowptr, deg,
                                           zscalar, E, n, nw, nbs2);

    // ---- Layer 1 (1 -> 64 -> 64): z from fused p4 aggregation ----
    mlp_kernel<<<nblk, 256, 0, stream>>>(zh16, zscalar, w1a, b1a,
                                         whi, wlo, b1a /*unused*/,
                                         whi /*slot0=w2a*/, wlo, b2a,
                                         hpre, hh16, stats, n, 0,
                                         /*write_hpre=*/0, /*write_hh=*/1);

    // ---- Layers 2-4: gatherz (fp16 in/out) + MLP ----
    for (int l = 1; l <= 3; ++l) {
        gatherz_kernel<<<(n + 3) / 4, 256, 0, stream>>>(hh16,
                                                        stats + (l - 1) * 128,
                                                        gammas + (l - 1) * HID,
                                                        betas + (l - 1) * HID,
                                                        rowptr, deg, csr_src, eps, l, zh16, n);
        mlp_kernel<<<nblk, 256, 0, stream>>>(zh16, zscalar, w1a, b1a,
                                             whi + (size_t)l * 4096,
                                             wlo + (size_t)l * 4096,
                                             b1s + (size_t)(l - 1) * HID,
                                             whi + (size_t)(3 + l) * 4096,
                                             wlo + (size_t)(3 + l) * 4096,
                                             b2s + (size_t)(l - 1) * HID,
                                             hpre, hh16, stats + l * 128,
                                             n, 1,
                                             /*write_hpre=*/(l == 3) ? 1 : 0,
                                             /*write_hh=*/(l < 3) ? 1 : 0);
    }
    final_kernel<<<(n + 3) / 4, 256, 0, stream>>>(hpre, stats + 3 * 128,
                                                  gammas + 3 * HID, betas + 3 * HID,
                                                  fcw, fcb, out, n);
}

// Round 8
// 357.343 us; speedup vs baseline: 1.1157x; 1.1157x over previous
//
#include <hip/hip_runtime.h>
#include <hip/hip_fp16.h>

#define HID 64
#define BN_EPS 1e-5f
#define WINSH 8          // 256 nodes per dst-window
#define WINSZ 256
#define B1 256           // bucketing blocks
#define PIT 72           // LDS pitch in shorts (16B-aligned fragment reads)

typedef short bf16x8 __attribute__((ext_vector_type(8)));
typedef float f32x4 __attribute__((ext_vector_type(4)));

__device__ __forceinline__ unsigned short f2b(float f) {
    unsigned int u = __float_as_uint(f);
    u = (u + 0x7FFF + ((u >> 16) & 1)) >> 16;   // RNE
    return (unsigned short)u;
}
__device__ __forceinline__ float b2f(unsigned short h) {
    return __uint_as_float(((unsigned int)h) << 16);
}
__device__ __forceinline__ f32x4 mfma_bf16(bf16x8 a, bf16x8 b, f32x4 c) {
    return __builtin_amdgcn_mfma_f32_16x16x32_bf16(a, b, c, 0, 0, 0);
}

// ---------------------------------------------------------------------------
// prep: blocks 0-6 = weight split; block 7 = zero stats; blocks 8+ = histogram
// ---------------------------------------------------------------------------
__global__ __launch_bounds__(256) void prep_kernel(const float* __restrict__ w2a,
                                                   const float* __restrict__ w1s,
                                                   const float* __restrict__ w2s,
                                                   unsigned short* __restrict__ whi,
                                                   unsigned short* __restrict__ wlo,
                                                   float* __restrict__ stats,
                                                   const int* __restrict__ dst,
                                                   int* __restrict__ cnt,
                                                   int E, int nw, int chunk) {
    int blk = blockIdx.x, tid = threadIdx.x;
    if (blk < 7) {
        const float* srcm = (blk == 0) ? w2a : (blk <= 3 ? w1s + (size_t)(blk - 1) * 4096
                                                         : w2s + (size_t)(blk - 4) * 4096);
        unsigned short* dh = whi + (size_t)blk * 4096;
        unsigned short* dl = wlo + (size_t)blk * 4096;
        for (int idx = tid; idx < 4096; idx += 256) {
            int j = idx & 7;
            int lane = (idx >> 3) & 63;
            int ntkh = idx >> 9;
            int nt = ntkh >> 1, kh = ntkh & 1;
            int nc = nt * 16 + (lane & 15);
            int k = kh * 32 + (lane >> 4) * 8 + j;
            float v = srcm[k * 64 + nc];
            unsigned short h = f2b(v);
            dh[idx] = h;
            dl[idx] = f2b(v - b2f(h));
        }
    } else if (blk == 7) {
        stats[tid] = 0.f;
        stats[tid + 256] = 0.f;
    } else {
        __shared__ int c[256];
        int b = blk - 8;
        c[tid] = 0;
        __syncthreads();
        int lo = b * chunk;
        int hi = lo + chunk; if (hi > E) hi = E;
        if ((((size_t)(dst + lo)) & 15) == 0) {
            int n4 = (hi - lo) >> 2;
            const int4* d4p = (const int4*)(dst + lo);
            for (int g = tid; g < n4; g += 256) {
                int4 d4 = d4p[g];
                atomicAdd(&c[d4.x >> WINSH], 1);
                atomicAdd(&c[d4.y >> WINSH], 1);
                atomicAdd(&c[d4.z >> WINSH], 1);
                atomicAdd(&c[d4.w >> WINSH], 1);
            }
            for (int e = lo + (n4 << 2) + tid; e < hi; e += 256)
                atomicAdd(&c[dst[e] >> WINSH], 1);
        } else {
            for (int e = lo + tid; e < hi; e += 256) atomicAdd(&c[dst[e] >> WINSH], 1);
        }
        __syncthreads();
        if (tid < nw) cnt[tid * B1 + b] = c[tid];
    }
}

// ---------------------------------------------------------------------------
// scan_a: per-256-cell block scan; emits partial prefixes + per-block sums.
// The tiny 196-wide scan of blocksums is recomputed locally inside p3/p4.
// ---------------------------------------------------------------------------
__global__ __launch_bounds__(256) void scan_a_kernel(const int* __restrict__ in,
                                                     int* __restrict__ partial,
                                                     int* __restrict__ blocksum, int n) {
    __shared__ int sums[256];
    int tid = threadIdx.x;
    int i = blockIdx.x * 256 + tid;
    int v = (i < n) ? in[i] : 0;
    sums[tid] = v;
    __syncthreads();
    for (int off = 1; off < 256; off <<= 1) {
        int t = (tid >= off) ? sums[tid - off] : 0;
        __syncthreads();
        sums[tid] += t;
        __syncthreads();
    }
    if (i < n) partial[i] = sums[tid] - v;
    if (tid == 255) blocksum[blockIdx.x] = sums[255];
}

__global__ __launch_bounds__(256) void p3_bucket_kernel(const int* __restrict__ src,
                                                        const int* __restrict__ dst,
                                                        const int* __restrict__ cpart,
                                                        const int* __restrict__ bsum,
                                                        int* __restrict__ ebuf,
                                                        int E, int nw, int chunk, int nbs2) {
    __shared__ int cur[256];
    __shared__ int sc[256];
    int tid = threadIdx.x, b = blockIdx.x;
    // local exclusive scan of bsum (nbs2 <= 256)
    int v = (tid < nbs2) ? bsum[tid] : 0;
    sc[tid] = v;
    __syncthreads();
    for (int off = 1; off < 256; off <<= 1) {
        int t = (tid >= off) ? sc[tid - off] : 0;
        __syncthreads();
        sc[tid] += t;
        __syncthreads();
    }
    int excl = sc[tid] - v;
    if (tid < nw) cur[tid] = cpart[tid * B1 + b] + excl;
    __syncthreads();
    int lo = b * chunk;
    int hi = lo + chunk; if (hi > E) hi = E;
    if (((((size_t)(dst + lo)) | ((size_t)(src + lo))) & 15) == 0) {
        int n4 = (hi - lo) >> 2;
        const int4* d4p = (const int4*)(dst + lo);
        const int4* s4p = (const int4*)(src + lo);
        for (int g = tid; g < n4; g += 256) {
            int4 d4 = d4p[g];
            int4 s4 = s4p[g];
            int p0 = atomicAdd(&cur[d4.x >> WINSH], 1);
            ebuf[p0] = s4.x | ((d4.x & (WINSZ - 1)) << 24);
            int p1 = atomicAdd(&cur[d4.y >> WINSH], 1);
            ebuf[p1] = s4.y | ((d4.y & (WINSZ - 1)) << 24);
            int p2 = atomicAdd(&cur[d4.z >> WINSH], 1);
            ebuf[p2] = s4.z | ((d4.z & (WINSZ - 1)) << 24);
            int p3 = atomicAdd(&cur[d4.w >> WINSH], 1);
            ebuf[p3] = s4.w | ((d4.w & (WINSZ - 1)) << 24);
        }
        for (int e = lo + (n4 << 2) + tid; e < hi; e += 256) {
            int d = dst[e];
            int pos = atomicAdd(&cur[d >> WINSH], 1);
            ebuf[pos] = src[e] | ((d & (WINSZ - 1)) << 24);
        }
    } else {
        for (int e = lo + tid; e < hi; e += 256) {
            int d = dst[e];
            int pos = atomicAdd(&cur[d >> WINSH], 1);
            ebuf[pos] = src[e] | ((d & (WINSZ - 1)) << 24);
        }
    }
}

// ---------------------------------------------------------------------------
// p4_fine: window-local counting sort into csr_src + layer-1 aggregation
// (xacc[dstlocal] += x[src], LDS float atomics) folded into the scatter.
// Emits rowptr/deg and zscalar = (1+eps0)*x + sum.
// ---------------------------------------------------------------------------
__global__ __launch_bounds__(256) void p4_fine_kernel(const int* __restrict__ ebuf,
                                                      const int* __restrict__ cpart,
                                                      const int* __restrict__ bsum,
                                                      const float* __restrict__ x,
                                                      const float* __restrict__ eps,
                                                      int* __restrict__ csr_src,
                                                      int* __restrict__ rowptr,
                                                      int* __restrict__ deg,
                                                      float* __restrict__ zscalar,
                                                      int E, int n, int nw, int nbs2) {
    __shared__ int fcnt[256];
    __shared__ int foff[256];
    __shared__ float xacc[256];
    int tid = threadIdx.x, w = blockIdx.x;
    // local exclusive scan of bsum -> blockoff values for w and w+1
    int bv = (tid < nbs2) ? bsum[tid] : 0;
    foff[tid] = bv;
    __syncthreads();
    for (int off = 1; off < 256; off <<= 1) {
        int t = (tid >= off) ? foff[tid - off] : 0;
        __syncthreads();
        foff[tid] += t;
        __syncthreads();
    }
    int excl = foff[tid] - bv;
    __syncthreads();
    foff[tid] = excl;
    __syncthreads();
    int lo = cpart[w * B1] + foff[w];
    int hi = (w + 1 < nw) ? cpart[(w + 1) * B1] + foff[w + 1] : E;
    __syncthreads();
    fcnt[tid] = 0;
    xacc[tid] = 0.f;
    __syncthreads();
    for (int e = lo + tid; e < hi; e += 256) atomicAdd(&fcnt[(unsigned)ebuf[e] >> 24], 1);
    __syncthreads();
    int v = fcnt[tid];
    foff[tid] = v;
    __syncthreads();
    for (int off = 1; off < 256; off <<= 1) {
        int t = (tid >= off) ? foff[tid - off] : 0;
        __syncthreads();
        foff[tid] += t;
        __syncthreads();
    }
    int myoff = lo + foff[tid] - v;
    int node = w * WINSZ + tid;
    if (node < n) { rowptr[node] = myoff; deg[node] = v; }
    __syncthreads();
    fcnt[tid] = myoff;
    __syncthreads();
    for (int e = lo + tid; e < hi; e += 256) {
        int p = ebuf[e];
        int s = p & 0xFFFFFF;
        int dl = (unsigned)p >> 24;
        int pos = atomicAdd(&fcnt[dl], 1);   // LDS atomic
        csr_src[pos] = s;
        atomicAdd(&xacc[dl], x[s]);          // LDS float atomic (layer-1 agg)
    }
    __syncthreads();
    if (node < n) zscalar[node] = fmaf(1.0f + eps[0], x[node], xacc[tid]);
}

// ---------------------------------------------------------------------------
// gatherz: half2 datapath, whole 128B rows (one cache line), self term from
// fp16 mirror, fp16 z output. BN of prev layer inline. 16-edge main loop
// keeps 8 independent row loads in flight per lane (latency hiding).
// csr_src addresses are wave-uniform -> scalarized by the compiler.
// ---------------------------------------------------------------------------
__global__ __launch_bounds__(256) void gatherz_kernel(const __half* __restrict__ hh16,
                                                      const float* __restrict__ stats_prev,
                                                      const float* __restrict__ gamma_prev,
                                                      const float* __restrict__ beta_prev,
                                                      const int* __restrict__ rowptr,
                                                      const int* __restrict__ deg,
                                                      const int* __restrict__ csr_src,
                                                      const float* __restrict__ eps,
                                                      int layer,
                                                      __half* __restrict__ zh16, int n) {
    int lane = threadIdx.x & 63;
    int half = lane >> 5;          // 0: even rows, 1: odd rows
    int fp = lane & 31;            // feature-pair index (features 2fp, 2fp+1)
    int node = blockIdx.x * 4 + (threadIdx.x >> 6);

    // BN params of previous layer for this feature pair
    float inv_n = 1.0f / (float)n;
    float2 sm = ((const float2*)stats_prev)[fp];
    float2 sq = ((const float2*)(stats_prev + 64))[fp];
    float2 gm = ((const float2*)gamma_prev)[fp];
    float2 bt = ((const float2*)beta_prev)[fp];
    float mux = sm.x * inv_n, muy = sm.y * inv_n;
    float scx = gm.x * rsqrtf(sq.x * inv_n - mux * mux + BN_EPS);
    float scy = gm.y * rsqrtf(sq.y * inv_n - muy * muy + BN_EPS);
    float shx = bt.x - mux * scx;
    float shy = bt.y - muy * scy;

    if (node >= n) return;
    int start = __builtin_amdgcn_readfirstlane(rowptr[node]);
    int cnt   = __builtin_amdgcn_readfirstlane(deg[node]);

    const __half2* hh2 = (const __half2*)hh16;   // row stride 32 half2
    float ax0 = 0.f, ay0 = 0.f, ax1 = 0.f, ay1 = 0.f;
    float ax2 = 0.f, ay2 = 0.f, ax3 = 0.f, ay3 = 0.f;
    float ax4 = 0.f, ay4 = 0.f, ax5 = 0.f, ay5 = 0.f;
    float ax6 = 0.f, ay6 = 0.f, ax7 = 0.f, ay7 = 0.f;
    int e = 0;
    for (; e + 16 <= cnt; e += 16) {
        int b0  = csr_src[start + e + 0];
        int b1  = csr_src[start + e + 1];
        int b2  = csr_src[start + e + 2];
        int b3  = csr_src[start + e + 3];
        int b4  = csr_src[start + e + 4];
        int b5  = csr_src[start + e + 5];
        int b6  = csr_src[start + e + 6];
        int b7  = csr_src[start + e + 7];
        int b8  = csr_src[start + e + 8];
        int b9  = csr_src[start + e + 9];
        int b10 = csr_src[start + e + 10];
        int b11 = csr_src[start + e + 11];
        int b12 = csr_src[start + e + 12];
        int b13 = csr_src[start + e + 13];
        int b14 = csr_src[start + e + 14];
        int b15 = csr_src[start + e + 15];
        int r0 = half ? b1  : b0;
        int r1 = half ? b3  : b2;
        int r2 = half ? b5  : b4;
        int r3 = half ? b7  : b6;
        int r4 = half ? b9  : b8;
        int r5 = half ? b11 : b10;
        int r6 = half ? b13 : b12;
        int r7 = half ? b15 : b14;
        float2 v0 = __half22float2(hh2[(size_t)r0 * 32 + fp]);
        float2 v1 = __half22float2(hh2[(size_t)r1 * 32 + fp]);
        float2 v2 = __half22float2(hh2[(size_t)r2 * 32 + fp]);
        float2 v3 = __half22float2(hh2[(size_t)r3 * 32 + fp]);
        float2 v4 = __half22float2(hh2[(size_t)r4 * 32 + fp]);
        float2 v5 = __half22float2(hh2[(size_t)r5 * 32 + fp]);
        float2 v6 = __half22float2(hh2[(size_t)r6 * 32 + fp]);
        float2 v7 = __half22float2(hh2[(size_t)r7 * 32 + fp]);
        ax0 += v0.x; ay0 += v0.y;
        ax1 += v1.x; ay1 += v1.y;
        ax2 += v2.x; ay2 += v2.y;
        ax3 += v3.x; ay3 += v3.y;
        ax4 += v4.x; ay4 += v4.y;
        ax5 += v5.x; ay5 += v5.y;
        ax6 += v6.x; ay6 += v6.y;
        ax7 += v7.x; ay7 += v7.y;
    }
    for (; e + 8 <= cnt; e += 8) {
        int s0 = csr_src[start + e + 0];
        int s1 = csr_src[start + e + 1];
        int s2 = csr_src[start + e + 2];
        int s3 = csr_src[start + e + 3];
        int s4 = csr_src[start + e + 4];
        int s5 = csr_src[start + e + 5];
        int s6 = csr_src[start + e + 6];
        int s7 = csr_src[start + e + 7];
        int r0 = half ? s1 : s0;
        int r1 = half ? s3 : s2;
        int r2 = half ? s5 : s4;
        int r3 = half ? s7 : s6;
        float2 v0 = __half22float2(hh2[(size_t)r0 * 32 + fp]);
        float2 v1 = __half22float2(hh2[(size_t)r1 * 32 + fp]);
        float2 v2 = __half22float2(hh2[(size_t)r2 * 32 + fp]);
        float2 v3 = __half22float2(hh2[(size_t)r3 * 32 + fp]);
        ax0 += v0.x; ay0 += v0.y;
        ax1 += v1.x; ay1 += v1.y;
        ax2 += v2.x; ay2 += v2.y;
        ax3 += v3.x; ay3 += v3.y;
    }
    for (; e < cnt; e += 2) {
        int idx = e + half;
        if (idx < cnt) {
            int s = csr_src[start + idx];
            float2 v = __half22float2(hh2[(size_t)s * 32 + fp]);
            ax0 += v.x; ay0 += v.y;
        }
    }
    float sx = ((ax0 + ax1) + (ax2 + ax3)) + ((ax4 + ax5) + (ax6 + ax7));
    float sy = ((ay0 + ay1) + (ay2 + ay3)) + ((ay4 + ay5) + (ay6 + ay7));
    sx += __shfl_xor(sx, 32);
    sy += __shfl_xor(sy, 32);

    float ep = 1.0f + eps[layer];
    float2 self = __half22float2(hh2[(size_t)node * 32 + fp]);
    float zx = fmaf(scx, fmaf(ep, self.x, sx), shx * (ep + (float)cnt));
    float zy = fmaf(scy, fmaf(ep, self.y, sy), shy * (ep + (float)cnt));
    if (half == 0) {
        ((__half2*)zh16)[(size_t)node * 32 + fp] = __floats2half2_rn(zx, zy);
    }
}

// ---------------------------------------------------------------------------
// MFMA MLP, split-bf16 precision. mode 1 stages from fp16 z via 16B loads
// (exact split of the fp16 value). Epilogue writes hh16 (layers 1-3) and/or
// hpre (layer 4).
// ---------------------------------------------------------------------------
__global__ __launch_bounds__(256) void mlp_kernel(const __half* __restrict__ zh16,
                                                  const float* __restrict__ zscalar,
                                                  const float* __restrict__ w1a,
                                                  const float* __restrict__ b1a,
                                                  const unsigned short* __restrict__ w1h,
                                                  const unsigned short* __restrict__ w1l,
                                                  const float* __restrict__ b1v,
                                                  const unsigned short* __restrict__ w2h,
                                                  const unsigned short* __restrict__ w2l,
                                                  const float* __restrict__ b2v,
                                                  float* __restrict__ hpre,
                                                  __half* __restrict__ hh16,
                                                  float* __restrict__ stats,
                                                  int n, int mode,
                                                  int write_hpre, int write_hh) {
    __shared__ __align__(16) unsigned short Ah[64 * PIT];
    __shared__ __align__(16) unsigned short Al[64 * PIT];
    __shared__ float ssum[64], ssq[64];

    int tid = threadIdx.x;
    int base = blockIdx.x * 64;

    if (mode) {
        const uint4* z128 = (const uint4*)zh16;   // 8 halfs per uint4; 8/row
        for (int i = tid; i < 512; i += 256) {
            int nn = i >> 3, q = i & 7;           // feature base q*8
            uint4 u = z128[(size_t)(base + nn) * 8 + q];
            const __half2* hv = (const __half2*)&u;   // 4 half2
            unsigned short hs[8], ls[8];
#pragma unroll
            for (int j = 0; j < 4; ++j) {
                float vx = __half2float(hv[j].x);
                float vy = __half2float(hv[j].y);
                unsigned short hx = f2b(vx);
                unsigned short hy = f2b(vy);
                hs[2 * j]     = hx;
                hs[2 * j + 1] = hy;
                ls[2 * j]     = f2b(vx - b2f(hx));
                ls[2 * j + 1] = f2b(vy - b2f(hy));
            }
            *(bf16x8*)&Ah[nn * PIT + q * 8] = *(const bf16x8*)hs;
            *(bf16x8*)&Al[nn * PIT + q * 8] = *(const bf16x8*)ls;
        }
    } else {
        for (int i = tid; i < 4096; i += 256) {
            int nn = i >> 6, k = i & 63;
            float zv = zscalar[base + nn];
            float v = fmaxf(fmaf(zv, w1a[k], b1a[k]), 0.f);
            unsigned short h = f2b(v);
            Ah[nn * PIT + k] = h;
            Al[nn * PIT + k] = f2b(v - b2f(h));
        }
    }
    if (tid < 64) { ssum[tid] = 0.f; ssq[tid] = 0.f; }
    __syncthreads();

    int l = tid & 63;
    int m = l & 15;            // A/B free index; D col
    int q = l >> 4;            // quad; D row block
    int m0 = (tid >> 6) * 16;  // wave's node-row block

    const bf16x8* a0h = (const bf16x8*)&Ah[(m0 + m) * PIT + q * 8];
    const bf16x8* a1h = (const bf16x8*)&Ah[(m0 + m) * PIT + 32 + q * 8];
    const bf16x8* a0l = (const bf16x8*)&Al[(m0 + m) * PIT + q * 8];
    const bf16x8* a1l = (const bf16x8*)&Al[(m0 + m) * PIT + 32 + q * 8];

    if (mode) {
        // GEMM1: T = relu(Z @ W1 + b1), split arithmetic
        bf16x8 xa0h = *a0h, xa1h = *a1h, xa0l = *a0l, xa1l = *a1l;
        f32x4 acc[4];
#pragma unroll
        for (int nt = 0; nt < 4; ++nt) {
            size_t fo0 = ((size_t)(nt * 2 + 0) * 64 + l) * 8;
            size_t fo1 = ((size_t)(nt * 2 + 1) * 64 + l) * 8;
            bf16x8 b0h = *(const bf16x8*)(w1h + fo0);
            bf16x8 b1h_ = *(const bf16x8*)(w1h + fo1);
            bf16x8 b0l = *(const bf16x8*)(w1l + fo0);
            bf16x8 b1l_ = *(const bf16x8*)(w1l + fo1);
            f32x4 c = {0.f, 0.f, 0.f, 0.f};
            c = mfma_bf16(xa0h, b0h, c);
            c = mfma_bf16(xa0h, b0l, c);
            c = mfma_bf16(xa0l, b0h, c);
            c = mfma_bf16(xa1h, b1h_, c);
            c = mfma_bf16(xa1h, b1l_, c);
            c = mfma_bf16(xa1l, b1h_, c);
            acc[nt] = c;
        }
#pragma unroll
        for (int nt = 0; nt < 4; ++nt) {
            int col = nt * 16 + m;
            float bv = b1v[col];
#pragma unroll
            for (int r = 0; r < 4; ++r) {
                int row = m0 + q * 4 + r;
                float T = fmaxf(acc[nt][r] + bv, 0.f);
                unsigned short h = f2b(T);
                Ah[row * PIT + col] = h;
                Al[row * PIT + col] = f2b(T - b2f(h));
            }
        }
    }
    __syncthreads();

    // GEMM2: H = relu(T @ W2 + b2), split arithmetic
    {
        bf16x8 xa0h = *a0h, xa1h = *a1h, xa0l = *a0l, xa1l = *a1l;
        f32x4 acc[4];
#pragma unroll
        for (int nt = 0; nt < 4; ++nt) {
            size_t fo0 = ((size_t)(nt * 2 + 0) * 64 + l) * 8;
            size_t fo1 = ((size_t)(nt * 2 + 1) * 64 + l) * 8;
            bf16x8 b0h = *(const bf16x8*)(w2h + fo0);
            bf16x8 b1h_ = *(const bf16x8*)(w2h + fo1);
            bf16x8 b0l = *(const bf16x8*)(w2l + fo0);
            bf16x8 b1l_ = *(const bf16x8*)(w2l + fo1);
            f32x4 c = {0.f, 0.f, 0.f, 0.f};
            c = mfma_bf16(xa0h, b0h, c);
            c = mfma_bf16(xa0h, b0l, c);
            c = mfma_bf16(xa0l, b0h, c);
            c = mfma_bf16(xa1h, b1h_, c);
            c = mfma_bf16(xa1h, b1l_, c);
            c = mfma_bf16(xa1l, b1h_, c);
            acc[nt] = c;
        }
#pragma unroll
        for (int nt = 0; nt < 4; ++nt) {
            int col = nt * 16 + m;
            float bv = b2v[col];
            float cs = 0.f, cq = 0.f;
#pragma unroll
            for (int r = 0; r < 4; ++r) {
                int node = base + m0 + q * 4 + r;
                float h = fmaxf(acc[nt][r] + bv, 0.f);
                if (node < n) {
                    if (write_hpre) hpre[(size_t)node * HID + col] = h;
                    if (write_hh) hh16[(size_t)node * HID + col] = __float2half(h);
                    cs += h;
                    cq = fmaf(h, h, cq);
                }
            }
            cs += __shfl_xor(cs, 16); cs += __shfl_xor(cs, 32);
            cq += __shfl_xor(cq, 16); cq += __shfl_xor(cq, 32);
            if (q == 0) {
                atomicAdd(&ssum[col], cs);
                atomicAdd(&ssq[col], cq);
            }
        }
    }
    __syncthreads();
    if (tid < 64) {
        atomicAdd(&stats[tid], ssum[tid]);
        atomicAdd(&stats[64 + tid], ssq[tid]);
    }
}

// ---------------------------------------------------------------------------
// Final: BN of layer 4 from stats + fc dot.
// ---------------------------------------------------------------------------
__global__ __launch_bounds__(256) void final_kernel(const float* __restrict__ hpre,
                                                    const float* __restrict__ stats,
                                                    const float* __restrict__ gamma,
                                                    const float* __restrict__ beta,
                                                    const float* __restrict__ fcw,
                                                    const float* __restrict__ fcb,
                                                    float* __restrict__ out, int n) {
    int wave = threadIdx.x >> 6;
    int lane = threadIdx.x & 63;
    int node = blockIdx.x * 4 + wave;
    if (node < n) {
        float inv_n = 1.0f / (float)n;
        float mu = stats[lane] * inv_n;
        float var = stats[64 + lane] * inv_n - mu * mu;
        float inv = rsqrtf(var + BN_EPS);
        float sc = gamma[lane] * inv;
        float sh = beta[lane] - mu * sc;
        float v = hpre[(size_t)node * HID + lane];
        float t = fmaf(v, sc, sh) * fcw[lane];
        for (int off = 32; off > 0; off >>= 1) t += __shfl_xor(t, off);
        if (lane == 0) out[node] = t + fcb[0];
    }
}

// ---------------------------------------------------------------------------
extern "C" void kernel_launch(void* const* d_in, const int* in_sizes, int n_in,
                              void* d_out, int out_size, void* d_ws, size_t ws_size,
                              hipStream_t stream) {
    const float* x      = (const float*)d_in[0];
    const int*   ei     = (const int*)d_in[1];
    const float* w1a    = (const float*)d_in[2];
    const float* b1a    = (const float*)d_in[3];
    const float* w2a    = (const float*)d_in[4];
    const float* b2a    = (const float*)d_in[5];
    const float* w1s    = (const float*)d_in[6];
    const float* b1s    = (const float*)d_in[7];
    const float* w2s    = (const float*)d_in[8];
    const float* b2s    = (const float*)d_in[9];
    const float* eps    = (const float*)d_in[10];
    const float* gammas = (const float*)d_in[11];
    const float* betas  = (const float*)d_in[12];
    const float* fcw    = (const float*)d_in[13];
    const float* fcb    = (const float*)d_in[14];
    float* out = (float*)d_out;

    int n = in_sizes[0];          // 50000
    int E = in_sizes[1] / 2;      // 1600000
    int npad = ((n + 63) / 64) * 64;
    int nblk = npad / 64;

    int nw = (n + WINSZ - 1) >> WINSH;      // 196 windows
    int NWB = nw * B1;
    int chunk = (((E + B1 - 1) / B1) + 3) & ~3;   // 4-aligned for int4 path
    int nbs2 = (NWB + 255) / 256;

    const int* src = ei;
    const int* dst = ei + E;

    char* p = (char*)d_ws;
    float* csrtmp  = (float*)p; p += (size_t)npad * HID * 4;   // CSR temps region
    float* hpre    = (float*)p; p += (size_t)npad * HID * 4;
    __half* hh16   = (__half*)p; p += (size_t)npad * HID * 2;
    __half* zh16   = (__half*)p; p += (size_t)npad * HID * 2;
    float* zscalar = (float*)p; p += (size_t)npad * 4;
    float* stats   = (float*)p; p += 4 * 128 * 4;
    unsigned short* whi = (unsigned short*)p; p += 7 * 4096 * 2;
    unsigned short* wlo = (unsigned short*)p; p += 7 * 4096 * 2;
    int* deg     = (int*)p; p += (size_t)n * 4;
    int* rowptr  = (int*)p; p += (size_t)n * 4;
    int* csr_src = (int*)p; p += (size_t)E * 4;

    // CSR-build temporaries live in csrtmp (dead after p4)
    int* ebuf     = (int*)csrtmp;
    int* cnt      = ebuf + E;
    int* cpart    = cnt + NWB;
    int* bsum     = cpart + NWB;

    // ---- prep (weights + stats zero + histogram) + CSR build ----
    prep_kernel<<<8 + B1, 256, 0, stream>>>(w2a, w1s, w2s, whi, wlo, stats,
                                            dst, cnt, E, nw, chunk);
    scan_a_kernel<<<nbs2, 256, 0, stream>>>(cnt, cpart, bsum, NWB);
    p3_bucket_kernel<<<B1, 256, 0, stream>>>(src, dst, cpart, bsum, ebuf, E, nw, chunk, nbs2);
    p4_fine_kernel<<<nw, 256, 0, stream>>>(ebuf, cpart, bsum, x, eps, csr_src, rowptr, deg,
                                           zscalar, E, n, nw, nbs2);

    // ---- Layer 1 (1 -> 64 -> 64): z from fused p4 aggregation ----
    mlp_kernel<<<nblk, 256, 0, stream>>>(zh16, zscalar, w1a, b1a,
                                         whi, wlo, b1a /*unused*/,
                                         whi /*slot0=w2a*/, wlo, b2a,
                                         hpre, hh16, stats, n, 0,
                                         /*write_hpre=*/0, /*write_hh=*/1);

    // ---- Layers 2-4: gatherz (fp16 in/out) + MLP ----
    for (int l = 1; l <= 3; ++l) {
        gatherz_kernel<<<(n + 3) / 4, 256, 0, stream>>>(hh16,
                                                        stats + (l - 1) * 128,
                                                        gammas + (l - 1) * HID,
                                                        betas + (l - 1) * HID,
                                                        rowptr, deg, csr_src, eps, l, zh16, n);
        mlp_kernel<<<nblk, 256, 0, stream>>>(zh16, zscalar, w1a, b1a,
                                             whi + (size_t)l * 4096,
                                             wlo + (size_t)l * 4096,
                                             b1s + (size_t)(l - 1) * HID,
                                             whi + (size_t)(3 + l) * 4096,
                                             wlo + (size_t)(3 + l) * 4096,
                                             b2s + (size_t)(l - 1) * HID,
                                             hpre, hh16, stats + l * 128,
                                             n, 1,
                                             /*write_hpre=*/(l == 3) ? 1 : 0,
                                             /*write_hh=*/(l < 3) ? 1 : 0);
    }
    final_kernel<<<(n + 3) / 4, 256, 0, stream>>>(hpre, stats + 3 * 128,
                                                  gammas + 3 * HID, betas + 3 * HID,
                                                  fcw, fcb, out, n);
}